// Round 1
// baseline (688.484 us; speedup 1.0000x reference)
//
#include <hip/hip_runtime.h>
#include <cstdint>
#include <cstddef>

// ---------------------------------------------------------------------------
// 2-layer GCN: out = A_hat @ relu(A_hat @ (x@W1) + b1) @ W2 + b2
// A_hat = D^{-1/2} (A + I) D^{-1/2}, edge weights w, self-loop weight 1.
// Pipeline per launch (graph-capture safe, ws re-poisoned each call):
//   1. init deg=1, count=0
//   2. edge pass: deg[dst]+=w, count[dst]+=1          (atomics, 1.6M edges)
//   3. dinv = rsqrt(deg)
//   4. exclusive scan of count -> rowstart (3-kernel block scan)
//   5. fill CSR: csrc[pos]=src, cnorm[pos]=dinv[s]*w*dinv[d]
//   6. h1 = x @ W1          (fp32 tiled GEMM)
//   7. a1 = relu(agg(h1) + b1)   (CSR gather, wave-per-node)
//   8. h2 = a1 @ W2
//   9. out = agg(h2) + b2
// ---------------------------------------------------------------------------

__global__ void init_kernel(float* deg, int* count, int n) {
  int i = blockIdx.x * 256 + threadIdx.x;
  if (i < n) { deg[i] = 1.0f; count[i] = 0; }
}

__global__ void deg_kernel(const int* __restrict__ dst, const float* __restrict__ w,
                           float* deg, int* count, int E) {
  int e = blockIdx.x * 256 + threadIdx.x;
  if (e < E) {
    int d = dst[e];
    atomicAdd(&deg[d], w[e]);
    atomicAdd(&count[d], 1);
  }
}

__global__ void dinv_kernel(const float* __restrict__ deg, float* dinv, int n) {
  int i = blockIdx.x * 256 + threadIdx.x;
  if (i < n) dinv[i] = rsqrtf(deg[i]);
}

// ---- 3-kernel exclusive scan of count[n] -> rowstart, chunk=1024/block ----
__global__ void scan1_kernel(const int* __restrict__ count, int* __restrict__ rowstart,
                             int* __restrict__ bsum, int n) {
  __shared__ int wsum[4];
  int b = blockIdx.x;
  int base = b * 1024;
  int tid = threadIdx.x;
  int lane = tid & 63, wv = tid >> 6;
  int idx = base + tid * 4;
  int v0 = (idx     < n) ? count[idx]     : 0;
  int v1 = (idx + 1 < n) ? count[idx + 1] : 0;
  int v2 = (idx + 2 < n) ? count[idx + 2] : 0;
  int v3 = (idx + 3 < n) ? count[idx + 3] : 0;
  int tsum = v0 + v1 + v2 + v3;
  int inc = tsum;
  #pragma unroll
  for (int off = 1; off < 64; off <<= 1) {
    int u = __shfl_up(inc, off, 64);
    if (lane >= off) inc += u;
  }
  if (lane == 63) wsum[wv] = inc;
  __syncthreads();
  int woff = 0;
  for (int w2 = 0; w2 < wv; ++w2) woff += wsum[w2];
  int texc = woff + inc - tsum;  // exclusive prefix of this thread's first elem
  if (idx     < n) rowstart[idx]     = texc;
  if (idx + 1 < n) rowstart[idx + 1] = texc + v0;
  if (idx + 2 < n) rowstart[idx + 2] = texc + v0 + v1;
  if (idx + 3 < n) rowstart[idx + 3] = texc + v0 + v1 + v2;
  if (tid == 255) bsum[b] = woff + inc;  // block total
}

__global__ void scan2_kernel(const int* __restrict__ bsum, int* __restrict__ boff, int nblk) {
  __shared__ int wsum[4];
  int tid = threadIdx.x, lane = tid & 63, wv = tid >> 6;
  int v = (tid < nblk) ? bsum[tid] : 0;
  int inc = v;
  #pragma unroll
  for (int off = 1; off < 64; off <<= 1) {
    int u = __shfl_up(inc, off, 64);
    if (lane >= off) inc += u;
  }
  if (lane == 63) wsum[wv] = inc;
  __syncthreads();
  int woff = 0;
  for (int w2 = 0; w2 < wv; ++w2) woff += wsum[w2];
  if (tid < nblk) boff[tid] = woff + inc - v;  // exclusive
}

__global__ void scan3_kernel(int* __restrict__ rowstart, int* __restrict__ cursor,
                             const int* __restrict__ boff, int n, int E) {
  int b = blockIdx.x;
  int base = b * 1024;
  int off = boff[b];
  for (int j = threadIdx.x; j < 1024; j += 256) {
    int i = base + j;
    if (i < n) { int r = rowstart[i] + off; rowstart[i] = r; cursor[i] = r; }
  }
  if (b == 0 && threadIdx.x == 0) rowstart[n] = E;
}

__global__ void fill_kernel(const int* __restrict__ src, const int* __restrict__ dst,
                            const float* __restrict__ w, const float* __restrict__ dinv,
                            int* cursor, int* __restrict__ csrc, float* __restrict__ cnorm,
                            int E) {
  int e = blockIdx.x * 256 + threadIdx.x;
  if (e < E) {
    int s = src[e], d = dst[e];
    int pos = atomicAdd(&cursor[d], 1);
    csrc[pos] = s;
    cnorm[pos] = dinv[s] * w[e] * dinv[d];
  }
}

// ---- fp32 GEMM: C[M,N] = A[M,128] @ W[128,N], tile 64x64, thread 4x4 ----
__global__ __launch_bounds__(256) void gemm_kernel(const float* __restrict__ A,
                                                   const float* __restrict__ W,
                                                   float* __restrict__ C, int M, int N) {
  __shared__ float As[128][64];  // [k][row] (transposed)
  __shared__ float Ws[128][64];  // [k][col]
  const int tid = threadIdx.x;
  const int tx = tid & 15;   // col group
  const int ty = tid >> 4;   // row group
  const int rowbase = blockIdx.x * 64;
  const int colbase = blockIdx.y * 64;

  // Stage A transposed. Mapping: row = i&63 varies fastest across lanes so the
  // LDS write As[k][row] is bank-parallel (bank=row%32, 2-way = free).
  for (int i = tid; i < 64 * 32; i += 256) {
    int row = i & 63;
    int k4 = (i >> 6) << 2;
    int gr = rowbase + row;
    float4 v = make_float4(0.f, 0.f, 0.f, 0.f);
    if (gr < M) v = *reinterpret_cast<const float4*>(A + (size_t)gr * 128 + k4);
    As[k4 + 0][row] = v.x;
    As[k4 + 1][row] = v.y;
    As[k4 + 2][row] = v.z;
    As[k4 + 3][row] = v.w;
  }
  // Stage W: contiguous float4 writes, aligned.
  for (int i = tid; i < 128 * 16; i += 256) {
    int c4 = (i & 15) << 2;
    int k = i >> 4;
    float4 v = *reinterpret_cast<const float4*>(W + (size_t)k * N + colbase + c4);
    *reinterpret_cast<float4*>(&Ws[k][c4]) = v;
  }
  __syncthreads();

  float acc[4][4] = {};
  #pragma unroll 8
  for (int k = 0; k < 128; ++k) {
    float4 a = *reinterpret_cast<const float4*>(&As[k][ty << 2]);
    float4 b = *reinterpret_cast<const float4*>(&Ws[k][tx << 2]);
    acc[0][0] += a.x * b.x; acc[0][1] += a.x * b.y; acc[0][2] += a.x * b.z; acc[0][3] += a.x * b.w;
    acc[1][0] += a.y * b.x; acc[1][1] += a.y * b.y; acc[1][2] += a.y * b.z; acc[1][3] += a.y * b.w;
    acc[2][0] += a.z * b.x; acc[2][1] += a.z * b.y; acc[2][2] += a.z * b.z; acc[2][3] += a.z * b.w;
    acc[3][0] += a.w * b.x; acc[3][1] += a.w * b.y; acc[3][2] += a.w * b.z; acc[3][3] += a.w * b.w;
  }
  #pragma unroll
  for (int r = 0; r < 4; ++r) {
    int gr = rowbase + (ty << 2) + r;
    if (gr < M) {
      *reinterpret_cast<float4*>(C + (size_t)gr * N + colbase + (tx << 2)) =
          make_float4(acc[r][0], acc[r][1], acc[r][2], acc[r][3]);
    }
  }
}

// ---- Aggregation: wave-per-node CSR gather. D=128: float2/lane ----
__global__ __launch_bounds__(256) void agg128_relu_kernel(
    const float* __restrict__ H, const int* __restrict__ rowstart,
    const int* __restrict__ csrc, const float* __restrict__ cnorm,
    const float* __restrict__ dinv, const float* __restrict__ bias,
    float* __restrict__ out, int n) {
  int wid = (blockIdx.x * 256 + threadIdx.x) >> 6;
  int lane = threadIdx.x & 63;
  if (wid >= n) return;
  float dv = dinv[wid];
  float ns = dv * dv;
  const float2* h2p = reinterpret_cast<const float2*>(H);
  float2 hv = h2p[(size_t)wid * 64 + lane];
  float a0 = ns * hv.x, a1 = ns * hv.y;
  int e0 = rowstart[wid], e1 = rowstart[wid + 1];
  int e = e0;
  // 2-way unroll: two independent gather chains in flight.
  for (; e + 1 < e1; e += 2) {
    int sA = csrc[e], sB = csrc[e + 1];
    float wA = cnorm[e], wB = cnorm[e + 1];
    float2 vA = h2p[(size_t)sA * 64 + lane];
    float2 vB = h2p[(size_t)sB * 64 + lane];
    a0 += wA * vA.x + wB * vB.x;
    a1 += wA * vA.y + wB * vB.y;
  }
  if (e < e1) {
    int sA = csrc[e];
    float wA = cnorm[e];
    float2 vA = h2p[(size_t)sA * 64 + lane];
    a0 += wA * vA.x;
    a1 += wA * vA.y;
  }
  a0 = fmaxf(a0 + bias[lane * 2], 0.f);
  a1 = fmaxf(a1 + bias[lane * 2 + 1], 0.f);
  reinterpret_cast<float2*>(out)[(size_t)wid * 64 + lane] = make_float2(a0, a1);
}

__global__ __launch_bounds__(256) void agg64_kernel(
    const float* __restrict__ H, const int* __restrict__ rowstart,
    const int* __restrict__ csrc, const float* __restrict__ cnorm,
    const float* __restrict__ dinv, const float* __restrict__ bias,
    float* __restrict__ out, int n) {
  int wid = (blockIdx.x * 256 + threadIdx.x) >> 6;
  int lane = threadIdx.x & 63;
  if (wid >= n) return;
  float dv = dinv[wid];
  float ns = dv * dv;
  float a0 = ns * H[(size_t)wid * 64 + lane];
  int e0 = rowstart[wid], e1 = rowstart[wid + 1];
  int e = e0;
  for (; e + 1 < e1; e += 2) {
    int sA = csrc[e], sB = csrc[e + 1];
    float wA = cnorm[e], wB = cnorm[e + 1];
    float vA = H[(size_t)sA * 64 + lane];
    float vB = H[(size_t)sB * 64 + lane];
    a0 += wA * vA + wB * vB;
  }
  if (e < e1) {
    a0 += cnorm[e] * H[(size_t)csrc[e] * 64 + lane];
  }
  out[(size_t)wid * 64 + lane] = a0 + bias[lane];
}

extern "C" void kernel_launch(void* const* d_in, const int* in_sizes, int n_in,
                              void* d_out, int out_size, void* d_ws, size_t ws_size,
                              hipStream_t stream) {
  const float* x  = (const float*)d_in[0];
  const int*   ei = (const int*)d_in[1];
  const float* ew = (const float*)d_in[2];
  const float* W1 = (const float*)d_in[3];
  const float* b1 = (const float*)d_in[4];
  const float* W2 = (const float*)d_in[5];
  const float* b2 = (const float*)d_in[6];
  float* out = (float*)d_out;
  const int N = in_sizes[0] / 128;
  const int E = in_sizes[2];
  const int* src = ei;
  const int* dst = ei + E;

  // Workspace layout (256B-aligned slices). Total ~143 MB (h2 aliases h1).
  char* wsB = (char*)d_ws;
  size_t off = 0;
  auto alloc = [&](size_t elems) {
    void* p = wsB + off;
    off += ((elems * 4 + 255) / 256) * 256;
    return p;
  };
  float* deg    = (float*)alloc(N);
  float* dinv   = (float*)alloc(N);
  int*   count  = (int*)alloc(N);
  int*   rowst  = (int*)alloc(N + 1);
  int*   cursor = (int*)alloc(N);
  int*   bsum   = (int*)alloc(256);
  int*   boff   = (int*)alloc(256);
  int*   csrc   = (int*)alloc(E);
  float* cnorm  = (float*)alloc(E);
  float* h1     = (float*)alloc((size_t)N * 128);
  float* a1     = (float*)alloc((size_t)N * 128);
  float* h2     = h1;  // h1 dead after agg1; reuse for layer-2 transform

  const int nb = (N + 255) / 256;
  const int eb = (E + 255) / 256;
  const int nblk = (N + 1023) / 1024;  // 98 <= 256 (scan2 single-block limit)

  init_kernel<<<nb, 256, 0, stream>>>(deg, count, N);
  deg_kernel<<<eb, 256, 0, stream>>>(dst, ew, deg, count, E);
  dinv_kernel<<<nb, 256, 0, stream>>>(deg, dinv, N);
  scan1_kernel<<<nblk, 256, 0, stream>>>(count, rowst, bsum, N);
  scan2_kernel<<<1, 256, 0, stream>>>(bsum, boff, nblk);
  scan3_kernel<<<nblk, 256, 0, stream>>>(rowst, cursor, boff, N, E);
  fill_kernel<<<eb, 256, 0, stream>>>(src, dst, ew, dinv, cursor, csrc, cnorm, E);

  dim3 g1((N + 63) / 64, 2);
  gemm_kernel<<<g1, 256, 0, stream>>>(x, W1, h1, N, 128);
  const int ab = (N + 3) / 4;
  agg128_relu_kernel<<<ab, 256, 0, stream>>>(h1, rowst, csrc, cnorm, dinv, b1, a1, N);
  dim3 g2((N + 63) / 64, 1);
  gemm_kernel<<<g2, 256, 0, stream>>>(a1, W2, h2, N, 64);
  agg64_kernel<<<ab, 256, 0, stream>>>(h2, rowst, csrc, cnorm, dinv, b2, out, N);
}

// Round 2
// 588.963 us; speedup vs baseline: 1.1690x; 1.1690x over previous
//
#include <hip/hip_runtime.h>
#include <cstdint>
#include <cstddef>

// ---------------------------------------------------------------------------
// 2-layer GCN: out = A_hat @ relu(A_hat @ (x@W1) + b1) @ W2 + b2
// A_hat = D^{-1/2} (A + I) D^{-1/2}, edge weights w, self-loop weight 1.
//
// CSR build with ONE atomic per edge (R2 change):
//   packed[d] : u64, bits 48..63 = incoming-edge count, bits 0..47 = fixed-
//               point (2^-32) weighted degree, initialized to 1.0 (self-loop).
//   degrank   : old = atomicAdd(packed[d], (1<<48)|fx(w)); rank[e] = old>>48.
//               (atomic write-through ~32B/op is the cost; was 3 atomics/edge,
//                now 1 -> predicted ~22 G atomics/s bound, ~80us)
//   fill      : pos = rowstart[d] + rank[e]   -- NO atomic.
// ---------------------------------------------------------------------------

typedef unsigned long long u64;
typedef unsigned short u16;

__global__ void init_kernel(u64* packed, int n) {
  int i = blockIdx.x * 256 + threadIdx.x;
  if (i < n) packed[i] = (1ull << 32);  // deg = 1.0 fixed-point, count = 0
}

__global__ void degrank_kernel(const int* __restrict__ dst, const float* __restrict__ w,
                               u64* packed, u16* __restrict__ rank, int E) {
  int e = blockIdx.x * 256 + threadIdx.x;
  if (e < E) {
    int d = dst[e];
    u64 add = (1ull << 48) | (u64)((double)w[e] * 4294967296.0);
    u64 old = atomicAdd(&packed[d], add);
    rank[e] = (u16)(old >> 48);
  }
}

__global__ void dinv_kernel(const u64* __restrict__ packed, float* dinv, int n) {
  int i = blockIdx.x * 256 + threadIdx.x;
  if (i < n) {
    float deg = (float)((double)(packed[i] & 0xFFFFFFFFFFFFull) * 2.3283064365386963e-10);
    dinv[i] = rsqrtf(deg);
  }
}

// ---- 3-kernel exclusive scan of counts (packed>>48) -> rowstart ----
__global__ void scan1_kernel(const u64* __restrict__ packed, int* __restrict__ rowstart,
                             int* __restrict__ bsum, int n) {
  __shared__ int wsum[4];
  int b = blockIdx.x;
  int base = b * 1024;
  int tid = threadIdx.x;
  int lane = tid & 63, wv = tid >> 6;
  int idx = base + tid * 4;
  int v0 = (idx     < n) ? (int)(packed[idx]     >> 48) : 0;
  int v1 = (idx + 1 < n) ? (int)(packed[idx + 1] >> 48) : 0;
  int v2 = (idx + 2 < n) ? (int)(packed[idx + 2] >> 48) : 0;
  int v3 = (idx + 3 < n) ? (int)(packed[idx + 3] >> 48) : 0;
  int tsum = v0 + v1 + v2 + v3;
  int inc = tsum;
  #pragma unroll
  for (int off = 1; off < 64; off <<= 1) {
    int u = __shfl_up(inc, off, 64);
    if (lane >= off) inc += u;
  }
  if (lane == 63) wsum[wv] = inc;
  __syncthreads();
  int woff = 0;
  for (int w2 = 0; w2 < wv; ++w2) woff += wsum[w2];
  int texc = woff + inc - tsum;
  if (idx     < n) rowstart[idx]     = texc;
  if (idx + 1 < n) rowstart[idx + 1] = texc + v0;
  if (idx + 2 < n) rowstart[idx + 2] = texc + v0 + v1;
  if (idx + 3 < n) rowstart[idx + 3] = texc + v0 + v1 + v2;
  if (tid == 255) bsum[b] = woff + inc;
}

__global__ void scan2_kernel(const int* __restrict__ bsum, int* __restrict__ boff, int nblk) {
  __shared__ int wsum[4];
  int tid = threadIdx.x, lane = tid & 63, wv = tid >> 6;
  int v = (tid < nblk) ? bsum[tid] : 0;
  int inc = v;
  #pragma unroll
  for (int off = 1; off < 64; off <<= 1) {
    int u = __shfl_up(inc, off, 64);
    if (lane >= off) inc += u;
  }
  if (lane == 63) wsum[wv] = inc;
  __syncthreads();
  int woff = 0;
  for (int w2 = 0; w2 < wv; ++w2) woff += wsum[w2];
  if (tid < nblk) boff[tid] = woff + inc - v;
}

__global__ void scan3_kernel(int* __restrict__ rowstart, const int* __restrict__ boff,
                             int n, int E) {
  int b = blockIdx.x;
  int base = b * 1024;
  int off = boff[b];
  for (int j = threadIdx.x; j < 1024; j += 256) {
    int i = base + j;
    if (i < n) rowstart[i] += off;
  }
  if (b == 0 && threadIdx.x == 0) rowstart[n] = E;
}

// ---- fill, atomic-free: pos = rowstart[dst] + rank ----
__global__ void fill_kernel(const int* __restrict__ src, const int* __restrict__ dst,
                            const float* __restrict__ w, const u16* __restrict__ rank,
                            const float* __restrict__ dinv, const int* __restrict__ rowstart,
                            int* __restrict__ csrc, float* __restrict__ cnorm, int E) {
  int e = blockIdx.x * 256 + threadIdx.x;
  if (e < E) {
    int s = src[e], d = dst[e];
    int pos = rowstart[d] + (int)rank[e];
    csrc[pos] = s;
    cnorm[pos] = dinv[s] * w[e] * dinv[d];
  }
}

// ---- fp32 GEMM: C[M,N] = A[M,128] @ W[128,N], tile 64x64, thread 4x4 ----
__global__ __launch_bounds__(256) void gemm_kernel(const float* __restrict__ A,
                                                   const float* __restrict__ W,
                                                   float* __restrict__ C, int M, int N) {
  __shared__ float As[128][64];  // [k][row] (transposed)
  __shared__ float Ws[128][64];  // [k][col]
  const int tid = threadIdx.x;
  const int tx = tid & 15;
  const int ty = tid >> 4;
  const int rowbase = blockIdx.x * 64;
  const int colbase = blockIdx.y * 64;

  for (int i = tid; i < 64 * 32; i += 256) {
    int row = i & 63;
    int k4 = (i >> 6) << 2;
    int gr = rowbase + row;
    float4 v = make_float4(0.f, 0.f, 0.f, 0.f);
    if (gr < M) v = *reinterpret_cast<const float4*>(A + (size_t)gr * 128 + k4);
    As[k4 + 0][row] = v.x;
    As[k4 + 1][row] = v.y;
    As[k4 + 2][row] = v.z;
    As[k4 + 3][row] = v.w;
  }
  for (int i = tid; i < 128 * 16; i += 256) {
    int c4 = (i & 15) << 2;
    int k = i >> 4;
    float4 v = *reinterpret_cast<const float4*>(W + (size_t)k * N + colbase + c4);
    *reinterpret_cast<float4*>(&Ws[k][c4]) = v;
  }
  __syncthreads();

  float acc[4][4] = {};
  #pragma unroll 8
  for (int k = 0; k < 128; ++k) {
    float4 a = *reinterpret_cast<const float4*>(&As[k][ty << 2]);
    float4 b = *reinterpret_cast<const float4*>(&Ws[k][tx << 2]);
    acc[0][0] += a.x * b.x; acc[0][1] += a.x * b.y; acc[0][2] += a.x * b.z; acc[0][3] += a.x * b.w;
    acc[1][0] += a.y * b.x; acc[1][1] += a.y * b.y; acc[1][2] += a.y * b.z; acc[1][3] += a.y * b.w;
    acc[2][0] += a.z * b.x; acc[2][1] += a.z * b.y; acc[2][2] += a.z * b.z; acc[2][3] += a.z * b.w;
    acc[3][0] += a.w * b.x; acc[3][1] += a.w * b.y; acc[3][2] += a.w * b.z; acc[3][3] += a.w * b.w;
  }
  #pragma unroll
  for (int r = 0; r < 4; ++r) {
    int gr = rowbase + (ty << 2) + r;
    if (gr < M) {
      *reinterpret_cast<float4*>(C + (size_t)gr * N + colbase + (tx << 2)) =
          make_float4(acc[r][0], acc[r][1], acc[r][2], acc[r][3]);
    }
  }
}

// ---- Aggregation: wave-per-node CSR gather. D=128: float2/lane ----
__global__ __launch_bounds__(256) void agg128_relu_kernel(
    const float* __restrict__ H, const int* __restrict__ rowstart,
    const int* __restrict__ csrc, const float* __restrict__ cnorm,
    const float* __restrict__ dinv, const float* __restrict__ bias,
    float* __restrict__ out, int n) {
  int wid = (blockIdx.x * 256 + threadIdx.x) >> 6;
  int lane = threadIdx.x & 63;
  if (wid >= n) return;
  float dv = dinv[wid];
  float ns = dv * dv;
  const float2* h2p = reinterpret_cast<const float2*>(H);
  float2 hv = h2p[(size_t)wid * 64 + lane];
  float a0 = ns * hv.x, a1 = ns * hv.y;
  int e0 = rowstart[wid], e1 = rowstart[wid + 1];
  int e = e0;
  for (; e + 1 < e1; e += 2) {
    int sA = csrc[e], sB = csrc[e + 1];
    float wA = cnorm[e], wB = cnorm[e + 1];
    float2 vA = h2p[(size_t)sA * 64 + lane];
    float2 vB = h2p[(size_t)sB * 64 + lane];
    a0 += wA * vA.x + wB * vB.x;
    a1 += wA * vA.y + wB * vB.y;
  }
  if (e < e1) {
    int sA = csrc[e];
    float wA = cnorm[e];
    float2 vA = h2p[(size_t)sA * 64 + lane];
    a0 += wA * vA.x;
    a1 += wA * vA.y;
  }
  a0 = fmaxf(a0 + bias[lane * 2], 0.f);
  a1 = fmaxf(a1 + bias[lane * 2 + 1], 0.f);
  reinterpret_cast<float2*>(out)[(size_t)wid * 64 + lane] = make_float2(a0, a1);
}

__global__ __launch_bounds__(256) void agg64_kernel(
    const float* __restrict__ H, const int* __restrict__ rowstart,
    const int* __restrict__ csrc, const float* __restrict__ cnorm,
    const float* __restrict__ dinv, const float* __restrict__ bias,
    float* __restrict__ out, int n) {
  int wid = (blockIdx.x * 256 + threadIdx.x) >> 6;
  int lane = threadIdx.x & 63;
  if (wid >= n) return;
  float dv = dinv[wid];
  float ns = dv * dv;
  float a0 = ns * H[(size_t)wid * 64 + lane];
  int e0 = rowstart[wid], e1 = rowstart[wid + 1];
  int e = e0;
  for (; e + 1 < e1; e += 2) {
    int sA = csrc[e], sB = csrc[e + 1];
    float wA = cnorm[e], wB = cnorm[e + 1];
    float vA = H[(size_t)sA * 64 + lane];
    float vB = H[(size_t)sB * 64 + lane];
    a0 += wA * vA + wB * vB;
  }
  if (e < e1) {
    a0 += cnorm[e] * H[(size_t)csrc[e] * 64 + lane];
  }
  out[(size_t)wid * 64 + lane] = a0 + bias[lane];
}

extern "C" void kernel_launch(void* const* d_in, const int* in_sizes, int n_in,
                              void* d_out, int out_size, void* d_ws, size_t ws_size,
                              hipStream_t stream) {
  const float* x  = (const float*)d_in[0];
  const int*   ei = (const int*)d_in[1];
  const float* ew = (const float*)d_in[2];
  const float* W1 = (const float*)d_in[3];
  const float* b1 = (const float*)d_in[4];
  const float* W2 = (const float*)d_in[5];
  const float* b2 = (const float*)d_in[6];
  float* out = (float*)d_out;
  const int N = in_sizes[0] / 128;
  const int E = in_sizes[2];
  const int* src = ei;
  const int* dst = ei + E;

  char* wsB = (char*)d_ws;
  size_t off = 0;
  auto alloc = [&](size_t bytes) {
    void* p = wsB + off;
    off += ((bytes + 255) / 256) * 256;
    return p;
  };
  u64*   packed = (u64*)alloc((size_t)N * 8);
  float* dinv   = (float*)alloc((size_t)N * 4);
  u16*   rank   = (u16*)alloc((size_t)E * 2);
  int*   rowst  = (int*)alloc((size_t)(N + 1) * 4);
  int*   bsum   = (int*)alloc(256 * 4);
  int*   boff   = (int*)alloc(256 * 4);
  int*   csrc   = (int*)alloc((size_t)E * 4);
  float* cnorm  = (float*)alloc((size_t)E * 4);
  float* h1     = (float*)alloc((size_t)N * 128 * 4);
  float* a1     = (float*)alloc((size_t)N * 128 * 4);
  float* h2     = h1;  // h1 dead after agg1

  const int nb = (N + 255) / 256;
  const int eb = (E + 255) / 256;
  const int nblk = (N + 1023) / 1024;  // 98 <= 256

  init_kernel<<<nb, 256, 0, stream>>>(packed, N);
  degrank_kernel<<<eb, 256, 0, stream>>>(dst, ew, packed, rank, E);
  dinv_kernel<<<nb, 256, 0, stream>>>(packed, dinv, N);
  scan1_kernel<<<nblk, 256, 0, stream>>>(packed, rowst, bsum, N);
  scan2_kernel<<<1, 256, 0, stream>>>(bsum, boff, nblk);
  scan3_kernel<<<nblk, 256, 0, stream>>>(rowst, boff, N, E);
  fill_kernel<<<eb, 256, 0, stream>>>(src, dst, ew, rank, dinv, rowst, csrc, cnorm, E);

  dim3 g1((N + 63) / 64, 2);
  gemm_kernel<<<g1, 256, 0, stream>>>(x, W1, h1, N, 128);
  const int ab = (N + 3) / 4;
  agg128_relu_kernel<<<ab, 256, 0, stream>>>(h1, rowst, csrc, cnorm, dinv, b1, a1, N);
  dim3 g2((N + 63) / 64, 1);
  gemm_kernel<<<g2, 256, 0, stream>>>(a1, W2, h2, N, 64);
  agg64_kernel<<<ab, 256, 0, stream>>>(h2, rowst, csrc, cnorm, dinv, b2, out, N);
}

// Round 5
// 543.123 us; speedup vs baseline: 1.2676x; 1.0844x over previous
//
#include <hip/hip_runtime.h>
#include <cstdint>
#include <cstddef>

// ---------------------------------------------------------------------------
// 2-layer GCN, bf16 intermediate storage (R3/R4):
//   h1 (x@W1), a1 (relu-agg), h2 (a1@W2) stored bf16 -> gather traffic halves.
//   All accumulation fp32. Final output fp32.
// CSR build: ONE atomic/edge (packed u64 count|fixed-point degree + rank).
// R4 fix: GEMM C-write epilogue was missing colbase (gemm1's second column
// block overwrote the first -> absmax 0.95). Restored.
// R5: identical to R4 (container infra failure, never ran).
// ---------------------------------------------------------------------------

typedef unsigned long long u64;
typedef unsigned int u32;
typedef unsigned short u16;

__device__ __forceinline__ float bflo(u32 u) { return __uint_as_float(u << 16); }
__device__ __forceinline__ float bfhi(u32 u) { return __uint_as_float(u & 0xffff0000u); }
__device__ __forceinline__ u32 f2bf(float f) {  // round-to-nearest-even
  u32 u = __float_as_uint(f);
  return (u + 0x7fffu + ((u >> 16) & 1u)) >> 16;
}
__device__ __forceinline__ u32 pack2bf(float lo, float hi) {
  return f2bf(lo) | (f2bf(hi) << 16);
}

__global__ void init_kernel(u64* packed, int n) {
  int i = blockIdx.x * 256 + threadIdx.x;
  if (i < n) packed[i] = (1ull << 32);  // deg = 1.0 fixed-point, count = 0
}

__global__ void degrank_kernel(const int* __restrict__ dst, const float* __restrict__ w,
                               u64* packed, u16* __restrict__ rank, int E) {
  int e = blockIdx.x * 256 + threadIdx.x;
  if (e < E) {
    int d = dst[e];
    u64 add = (1ull << 48) | (u64)((double)w[e] * 4294967296.0);
    u64 old = atomicAdd(&packed[d], add);
    rank[e] = (u16)(old >> 48);
  }
}

__global__ void dinv_kernel(const u64* __restrict__ packed, float* dinv, int n) {
  int i = blockIdx.x * 256 + threadIdx.x;
  if (i < n) {
    float deg = (float)((double)(packed[i] & 0xFFFFFFFFFFFFull) * 2.3283064365386963e-10);
    dinv[i] = rsqrtf(deg);
  }
}

// ---- 3-kernel exclusive scan of counts (packed>>48) -> rowstart ----
__global__ void scan1_kernel(const u64* __restrict__ packed, int* __restrict__ rowstart,
                             int* __restrict__ bsum, int n) {
  __shared__ int wsum[4];
  int b = blockIdx.x;
  int base = b * 1024;
  int tid = threadIdx.x;
  int lane = tid & 63, wv = tid >> 6;
  int idx = base + tid * 4;
  int v0 = (idx     < n) ? (int)(packed[idx]     >> 48) : 0;
  int v1 = (idx + 1 < n) ? (int)(packed[idx + 1] >> 48) : 0;
  int v2 = (idx + 2 < n) ? (int)(packed[idx + 2] >> 48) : 0;
  int v3 = (idx + 3 < n) ? (int)(packed[idx + 3] >> 48) : 0;
  int tsum = v0 + v1 + v2 + v3;
  int inc = tsum;
  #pragma unroll
  for (int off = 1; off < 64; off <<= 1) {
    int u = __shfl_up(inc, off, 64);
    if (lane >= off) inc += u;
  }
  if (lane == 63) wsum[wv] = inc;
  __syncthreads();
  int woff = 0;
  for (int w2 = 0; w2 < wv; ++w2) woff += wsum[w2];
  int texc = woff + inc - tsum;
  if (idx     < n) rowstart[idx]     = texc;
  if (idx + 1 < n) rowstart[idx + 1] = texc + v0;
  if (idx + 2 < n) rowstart[idx + 2] = texc + v0 + v1;
  if (idx + 3 < n) rowstart[idx + 3] = texc + v0 + v1 + v2;
  if (tid == 255) bsum[b] = woff + inc;
}

__global__ void scan2_kernel(const int* __restrict__ bsum, int* __restrict__ boff, int nblk) {
  __shared__ int wsum[4];
  int tid = threadIdx.x, lane = tid & 63, wv = tid >> 6;
  int v = (tid < nblk) ? bsum[tid] : 0;
  int inc = v;
  #pragma unroll
  for (int off = 1; off < 64; off <<= 1) {
    int u = __shfl_up(inc, off, 64);
    if (lane >= off) inc += u;
  }
  if (lane == 63) wsum[wv] = inc;
  __syncthreads();
  int woff = 0;
  for (int w2 = 0; w2 < wv; ++w2) woff += wsum[w2];
  if (tid < nblk) boff[tid] = woff + inc - v;
}

__global__ void scan3_kernel(int* __restrict__ rowstart, const int* __restrict__ boff,
                             int n, int E) {
  int b = blockIdx.x;
  int base = b * 1024;
  int off = boff[b];
  for (int j = threadIdx.x; j < 1024; j += 256) {
    int i = base + j;
    if (i < n) rowstart[i] += off;
  }
  if (b == 0 && threadIdx.x == 0) rowstart[n] = E;
}

// ---- fill, atomic-free: pos = rowstart[dst] + rank ----
__global__ void fill_kernel(const int* __restrict__ src, const int* __restrict__ dst,
                            const float* __restrict__ w, const u16* __restrict__ rank,
                            const float* __restrict__ dinv, const int* __restrict__ rowstart,
                            int* __restrict__ csrc, float* __restrict__ cnorm, int E) {
  int e = blockIdx.x * 256 + threadIdx.x;
  if (e < E) {
    int s = src[e], d = dst[e];
    int pos = rowstart[d] + (int)rank[e];
    csrc[pos] = s;
    cnorm[pos] = dinv[s] * w[e] * dinv[d];
  }
}

// ---- GEMM: C[M,N](bf16) = A[M,128] @ W[128,N], tile 64x64, thread 4x4 ----
// A fp32 (layer 1) or bf16 (layer 2), staged to fp32 LDS. K fixed = 128.
template <bool A_BF16>
__global__ __launch_bounds__(256) void gemm_kernel(const void* __restrict__ Av,
                                                   const float* __restrict__ W,
                                                   u16* __restrict__ C, int M, int N) {
  __shared__ float As[128][64];  // [k][row] (transposed)
  __shared__ float Ws[128][64];  // [k][col]
  const int tid = threadIdx.x;
  const int tx = tid & 15;
  const int ty = tid >> 4;
  const int rowbase = blockIdx.x * 64;
  const int colbase = blockIdx.y * 64;

  // Stage A transposed; row varies fastest across lanes -> bank-parallel writes.
  for (int i = tid; i < 64 * 32; i += 256) {
    int row = i & 63;
    int chunk = i >> 6;       // 0..31, covers 4 k each
    int k4 = chunk << 2;
    int gr = rowbase + row;
    float f0 = 0.f, f1 = 0.f, f2 = 0.f, f3 = 0.f;
    if (gr < M) {
      if constexpr (A_BF16) {
        const u32* arow = reinterpret_cast<const u32*>((const u16*)Av + (size_t)gr * 128);
        uint2 u = reinterpret_cast<const uint2*>(arow)[chunk];
        f0 = bflo(u.x); f1 = bfhi(u.x); f2 = bflo(u.y); f3 = bfhi(u.y);
      } else {
        float4 v = *reinterpret_cast<const float4*>((const float*)Av + (size_t)gr * 128 + k4);
        f0 = v.x; f1 = v.y; f2 = v.z; f3 = v.w;
      }
    }
    As[k4 + 0][row] = f0;
    As[k4 + 1][row] = f1;
    As[k4 + 2][row] = f2;
    As[k4 + 3][row] = f3;
  }
  for (int i = tid; i < 128 * 16; i += 256) {
    int c4 = (i & 15) << 2;
    int k = i >> 4;
    float4 v = *reinterpret_cast<const float4*>(W + (size_t)k * N + colbase + c4);
    *reinterpret_cast<float4*>(&Ws[k][c4]) = v;
  }
  __syncthreads();

  float acc[4][4] = {};
  #pragma unroll 8
  for (int k = 0; k < 128; ++k) {
    float4 a = *reinterpret_cast<const float4*>(&As[k][ty << 2]);
    float4 b = *reinterpret_cast<const float4*>(&Ws[k][tx << 2]);
    acc[0][0] += a.x * b.x; acc[0][1] += a.x * b.y; acc[0][2] += a.x * b.z; acc[0][3] += a.x * b.w;
    acc[1][0] += a.y * b.x; acc[1][1] += a.y * b.y; acc[1][2] += a.y * b.z; acc[1][3] += a.y * b.w;
    acc[2][0] += a.z * b.x; acc[2][1] += a.z * b.y; acc[2][2] += a.z * b.z; acc[2][3] += a.z * b.w;
    acc[3][0] += a.w * b.x; acc[3][1] += a.w * b.y; acc[3][2] += a.w * b.z; acc[3][3] += a.w * b.w;
  }
  #pragma unroll
  for (int r = 0; r < 4; ++r) {
    int gr = rowbase + (ty << 2) + r;
    if (gr < M) {
      uint2 p;
      p.x = pack2bf(acc[r][0], acc[r][1]);
      p.y = pack2bf(acc[r][2], acc[r][3]);
      *reinterpret_cast<uint2*>(C + (size_t)gr * N + colbase + (tx << 2)) = p;
    }
  }
}

// ---- Aggregation layer 1: bf16 gather (D=128, row=256B), bf16 out ----
__global__ __launch_bounds__(256) void agg128_relu_kernel(
    const u32* __restrict__ H, const int* __restrict__ rowstart,
    const int* __restrict__ csrc, const float* __restrict__ cnorm,
    const float* __restrict__ dinv, const float* __restrict__ bias,
    u32* __restrict__ out, int n) {
  int wid = (blockIdx.x * 256 + threadIdx.x) >> 6;
  int lane = threadIdx.x & 63;
  if (wid >= n) return;
  float dv = dinv[wid];
  float ns = dv * dv;
  u32 hv = H[(size_t)wid * 64 + lane];
  float a0 = ns * bflo(hv), a1 = ns * bfhi(hv);
  int e0 = rowstart[wid], e1 = rowstart[wid + 1];
  int e = e0;
  for (; e + 1 < e1; e += 2) {
    int sA = csrc[e], sB = csrc[e + 1];
    float wA = cnorm[e], wB = cnorm[e + 1];
    u32 vA = H[(size_t)sA * 64 + lane];
    u32 vB = H[(size_t)sB * 64 + lane];
    a0 += wA * bflo(vA) + wB * bflo(vB);
    a1 += wA * bfhi(vA) + wB * bfhi(vB);
  }
  if (e < e1) {
    u32 vA = H[(size_t)csrc[e] * 64 + lane];
    float wA = cnorm[e];
    a0 += wA * bflo(vA);
    a1 += wA * bfhi(vA);
  }
  a0 = fmaxf(a0 + bias[lane * 2], 0.f);
  a1 = fmaxf(a1 + bias[lane * 2 + 1], 0.f);
  out[(size_t)wid * 64 + lane] = pack2bf(a0, a1);
}

// ---- Aggregation layer 2: bf16 gather (D=64, row=128B), fp32 out ----
__global__ __launch_bounds__(256) void agg64_kernel(
    const u16* __restrict__ H, const int* __restrict__ rowstart,
    const int* __restrict__ csrc, const float* __restrict__ cnorm,
    const float* __restrict__ dinv, const float* __restrict__ bias,
    float* __restrict__ out, int n) {
  int wid = (blockIdx.x * 256 + threadIdx.x) >> 6;
  int lane = threadIdx.x & 63;
  if (wid >= n) return;
  float dv = dinv[wid];
  float ns = dv * dv;
  float a0 = ns * bflo((u32)H[(size_t)wid * 64 + lane]);
  int e0 = rowstart[wid], e1 = rowstart[wid + 1];
  int e = e0;
  for (; e + 1 < e1; e += 2) {
    int sA = csrc[e], sB = csrc[e + 1];
    float wA = cnorm[e], wB = cnorm[e + 1];
    float vA = bflo((u32)H[(size_t)sA * 64 + lane]);
    float vB = bflo((u32)H[(size_t)sB * 64 + lane]);
    a0 += wA * vA + wB * vB;
  }
  if (e < e1) {
    a0 += cnorm[e] * bflo((u32)H[(size_t)csrc[e] * 64 + lane]);
  }
  out[(size_t)wid * 64 + lane] = a0 + bias[lane];
}

extern "C" void kernel_launch(void* const* d_in, const int* in_sizes, int n_in,
                              void* d_out, int out_size, void* d_ws, size_t ws_size,
                              hipStream_t stream) {
  const float* x  = (const float*)d_in[0];
  const int*   ei = (const int*)d_in[1];
  const float* ew = (const float*)d_in[2];
  const float* W1 = (const float*)d_in[3];
  const float* b1 = (const float*)d_in[4];
  const float* W2 = (const float*)d_in[5];
  const float* b2 = (const float*)d_in[6];
  float* out = (float*)d_out;
  const int N = in_sizes[0] / 128;
  const int E = in_sizes[2];
  const int* src = ei;
  const int* dst = ei + E;

  char* wsB = (char*)d_ws;
  size_t off = 0;
  auto alloc = [&](size_t bytes) {
    void* p = wsB + off;
    off += ((bytes + 255) / 256) * 256;
    return p;
  };
  u64*   packed = (u64*)alloc((size_t)N * 8);
  float* dinv   = (float*)alloc((size_t)N * 4);
  u16*   rank   = (u16*)alloc((size_t)E * 2);
  int*   rowst  = (int*)alloc((size_t)(N + 1) * 4);
  int*   bsum   = (int*)alloc(256 * 4);
  int*   boff   = (int*)alloc(256 * 4);
  int*   csrc   = (int*)alloc((size_t)E * 4);
  float* cnorm  = (float*)alloc((size_t)E * 4);
  u16*   h1     = (u16*)alloc((size_t)N * 128 * 2);  // bf16
  u16*   a1     = (u16*)alloc((size_t)N * 128 * 2);  // bf16
  u16*   h2     = h1;  // h1 dead after agg1; reuse (N*64*2 <= N*128*2)

  const int nb = (N + 255) / 256;
  const int eb = (E + 255) / 256;
  const int nblk = (N + 1023) / 1024;  // 98 <= 256

  init_kernel<<<nb, 256, 0, stream>>>(packed, N);
  degrank_kernel<<<eb, 256, 0, stream>>>(dst, ew, packed, rank, E);
  dinv_kernel<<<nb, 256, 0, stream>>>(packed, dinv, N);
  scan1_kernel<<<nblk, 256, 0, stream>>>(packed, rowst, bsum, N);
  scan2_kernel<<<1, 256, 0, stream>>>(bsum, boff, nblk);
  scan3_kernel<<<nblk, 256, 0, stream>>>(rowst, boff, N, E);
  fill_kernel<<<eb, 256, 0, stream>>>(src, dst, ew, rank, dinv, rowst, csrc, cnorm, E);

  dim3 g1((N + 63) / 64, 2);
  gemm_kernel<false><<<g1, 256, 0, stream>>>(x, W1, h1, N, 128);
  const int ab = (N + 3) / 4;
  agg128_relu_kernel<<<ab, 256, 0, stream>>>((const u32*)h1, rowst, csrc, cnorm, dinv, b1,
                                             (u32*)a1, N);
  dim3 g2((N + 63) / 64, 1);
  gemm_kernel<true><<<g2, 256, 0, stream>>>(a1, W2, h2, N, 64);
  agg64_kernel<<<ab, 256, 0, stream>>>(h2, rowst, csrc, cnorm, dinv, b2, out, N);
}

// Round 8
// 461.918 us; speedup vs baseline: 1.4905x; 1.1758x over previous
//
#include <hip/hip_runtime.h>
#include <cstdint>
#include <cstddef>

// ---------------------------------------------------------------------------
// 2-layer GCN, bf16 intermediates. R6/R7/R8:
//  - degrank fused with gemm1 (independent chains; atomics are coherence-
//    point-bound so gemm rides along ~free)
//  - dinv fused into scan1
//  - edge records packed (src,norm) int2 -> one uniform load per edge
//  - agg loops 4-way unrolled for memory-level parallelism
// ---------------------------------------------------------------------------

typedef unsigned long long u64;
typedef unsigned int u32;
typedef unsigned short u16;

__device__ __forceinline__ float bflo(u32 u) { return __uint_as_float(u << 16); }
__device__ __forceinline__ float bfhi(u32 u) { return __uint_as_float(u & 0xffff0000u); }
__device__ __forceinline__ u32 f2bf(float f) {  // round-to-nearest-even
  u32 u = __float_as_uint(f);
  return (u + 0x7fffu + ((u >> 16) & 1u)) >> 16;
}
__device__ __forceinline__ u32 pack2bf(float lo, float hi) {
  return f2bf(lo) | (f2bf(hi) << 16);
}

__global__ void init_kernel(u64* packed, int n) {
  int i = blockIdx.x * 256 + threadIdx.x;
  if (i < n) packed[i] = (1ull << 32);  // deg = 1.0 fixed-point, count = 0
}

// ---- fused: blocks [0, degBlocks) do degrank; rest do gemm1 (x@W1->bf16) ----
__global__ __launch_bounds__(256) void fused_dg_kernel(
    const int* __restrict__ dst, const float* __restrict__ ew,
    u64* packed, u16* __restrict__ rank, int E, int degBlocks,
    const float* __restrict__ x, const float* __restrict__ W1,
    u16* __restrict__ h1, int M) {
  if ((int)blockIdx.x < degBlocks) {
    int e = blockIdx.x * 256 + threadIdx.x;
    if (e < E) {
      int d = dst[e];
      u64 add = (1ull << 48) | (u64)((double)ew[e] * 4294967296.0);
      u64 old = atomicAdd(&packed[d], add);
      rank[e] = (u16)(old >> 48);
    }
    return;
  }
  // ---- gemm1: C[M,128](bf16) = x[M,128] @ W1[128,128], tile 64x64 ----
  __shared__ float As[128][64];  // [k][row]
  __shared__ float Ws[128][64];  // [k][col]
  const int gb = blockIdx.x - degBlocks;
  const int nbx = (M + 63) >> 6;
  const int bx = gb % nbx;
  const int by = gb / nbx;  // 0 or 1
  const int tid = threadIdx.x;
  const int tx = tid & 15;
  const int ty = tid >> 4;
  const int rowbase = bx * 64;
  const int colbase = by * 64;

  for (int i = tid; i < 64 * 32; i += 256) {
    int row = i & 63;
    int k4 = (i >> 6) << 2;
    int gr = rowbase + row;
    float4 v = make_float4(0.f, 0.f, 0.f, 0.f);
    if (gr < M) v = *reinterpret_cast<const float4*>(x + (size_t)gr * 128 + k4);
    As[k4 + 0][row] = v.x;
    As[k4 + 1][row] = v.y;
    As[k4 + 2][row] = v.z;
    As[k4 + 3][row] = v.w;
  }
  for (int i = tid; i < 128 * 16; i += 256) {
    int c4 = (i & 15) << 2;
    int k = i >> 4;
    float4 v = *reinterpret_cast<const float4*>(W1 + (size_t)k * 128 + colbase + c4);
    *reinterpret_cast<float4*>(&Ws[k][c4]) = v;
  }
  __syncthreads();

  float acc[4][4] = {};
  #pragma unroll 8
  for (int k = 0; k < 128; ++k) {
    float4 a = *reinterpret_cast<const float4*>(&As[k][ty << 2]);
    float4 b = *reinterpret_cast<const float4*>(&Ws[k][tx << 2]);
    acc[0][0] += a.x * b.x; acc[0][1] += a.x * b.y; acc[0][2] += a.x * b.z; acc[0][3] += a.x * b.w;
    acc[1][0] += a.y * b.x; acc[1][1] += a.y * b.y; acc[1][2] += a.y * b.z; acc[1][3] += a.y * b.w;
    acc[2][0] += a.z * b.x; acc[2][1] += a.z * b.y; acc[2][2] += a.z * b.z; acc[2][3] += a.z * b.w;
    acc[3][0] += a.w * b.x; acc[3][1] += a.w * b.y; acc[3][2] += a.w * b.z; acc[3][3] += a.w * b.w;
  }
  #pragma unroll
  for (int r = 0; r < 4; ++r) {
    int gr = rowbase + (ty << 2) + r;
    if (gr < M) {
      uint2 p;
      p.x = pack2bf(acc[r][0], acc[r][1]);
      p.y = pack2bf(acc[r][2], acc[r][3]);
      *reinterpret_cast<uint2*>(h1 + (size_t)gr * 128 + colbase + (tx << 2)) = p;
    }
  }
}

// ---- scan1 (+dinv): exclusive scan of counts (packed>>48) -> rowstart ----
__global__ void scan1_kernel(const u64* __restrict__ packed, int* __restrict__ rowstart,
                             int* __restrict__ bsum, float* __restrict__ dinvp, int n) {
  __shared__ int wsum[4];
  int b = blockIdx.x;
  int base = b * 1024;
  int tid = threadIdx.x;
  int lane = tid & 63, wv = tid >> 6;
  int idx = base + tid * 4;
  int v0 = 0, v1 = 0, v2 = 0, v3 = 0;
  #pragma unroll
  for (int j = 0; j < 4; ++j) {
    if (idx + j < n) {
      u64 p = packed[idx + j];
      int c = (int)(p >> 48);
      if (j == 0) v0 = c; else if (j == 1) v1 = c; else if (j == 2) v2 = c; else v3 = c;
      float deg = (float)((double)(p & 0xFFFFFFFFFFFFull) * 2.3283064365386963e-10);
      dinvp[idx + j] = rsqrtf(deg);
    }
  }
  int tsum = v0 + v1 + v2 + v3;
  int inc = tsum;
  #pragma unroll
  for (int off = 1; off < 64; off <<= 1) {
    int u = __shfl_up(inc, off, 64);
    if (lane >= off) inc += u;
  }
  if (lane == 63) wsum[wv] = inc;
  __syncthreads();
  int woff = 0;
  for (int w2 = 0; w2 < wv; ++w2) woff += wsum[w2];
  int texc = woff + inc - tsum;
  if (idx     < n) rowstart[idx]     = texc;
  if (idx + 1 < n) rowstart[idx + 1] = texc + v0;
  if (idx + 2 < n) rowstart[idx + 2] = texc + v0 + v1;
  if (idx + 3 < n) rowstart[idx + 3] = texc + v0 + v1 + v2;
  if (tid == 255) bsum[b] = woff + inc;
}

__global__ void scan2_kernel(const int* __restrict__ bsum, int* __restrict__ boff, int nblk) {
  __shared__ int wsum[4];
  int tid = threadIdx.x, lane = tid & 63, wv = tid >> 6;
  int v = (tid < nblk) ? bsum[tid] : 0;
  int inc = v;
  #pragma unroll
  for (int off = 1; off < 64; off <<= 1) {
    int u = __shfl_up(inc, off, 64);
    if (lane >= off) inc += u;
  }
  if (lane == 63) wsum[wv] = inc;
  __syncthreads();
  int woff = 0;
  for (int w2 = 0; w2 < wv; ++w2) woff += wsum[w2];
  if (tid < nblk) boff[tid] = woff + inc - v;
}

__global__ void scan3_kernel(int* __restrict__ rowstart, const int* __restrict__ boff,
                             int n, int E) {
  int b = blockIdx.x;
  int base = b * 1024;
  int off = boff[b];
  for (int j = threadIdx.x; j < 1024; j += 256) {
    int i = base + j;
    if (i < n) rowstart[i] += off;
  }
  if (b == 0 && threadIdx.x == 0) rowstart[n] = E;
}

// ---- fill: erec[pos] = (src, dinv[s]*w*dinv[d]) -- no atomics ----
__global__ void fill_kernel(const int* __restrict__ src, const int* __restrict__ dst,
                            const float* __restrict__ w, const u16* __restrict__ rank,
                            const float* __restrict__ dinv, const int* __restrict__ rowstart,
                            int2* __restrict__ erec, int E) {
  int e = blockIdx.x * 256 + threadIdx.x;
  if (e < E) {
    int s = src[e], d = dst[e];
    int pos = rowstart[d] + (int)rank[e];
    float nrm = dinv[s] * w[e] * dinv[d];
    erec[pos] = make_int2(s, __float_as_int(nrm));
  }
}

// ---- gemm2: C[M,64](bf16) = a1[M,128](bf16) @ W2[128,64] ----
__global__ __launch_bounds__(256) void gemm2_kernel(const u16* __restrict__ A,
                                                    const float* __restrict__ W,
                                                    u16* __restrict__ C, int M) {
  __shared__ float As[128][64];
  __shared__ float Ws[128][64];
  const int tid = threadIdx.x;
  const int tx = tid & 15;
  const int ty = tid >> 4;
  const int rowbase = blockIdx.x * 64;

  for (int i = tid; i < 64 * 32; i += 256) {
    int row = i & 63;
    int chunk = i >> 6;
    int k4 = chunk << 2;
    int gr = rowbase + row;
    float f0 = 0.f, f1 = 0.f, f2 = 0.f, f3 = 0.f;
    if (gr < M) {
      uint2 u = reinterpret_cast<const uint2*>(A + (size_t)gr * 128)[chunk];
      f0 = bflo(u.x); f1 = bfhi(u.x); f2 = bflo(u.y); f3 = bfhi(u.y);
    }
    As[k4 + 0][row] = f0;
    As[k4 + 1][row] = f1;
    As[k4 + 2][row] = f2;
    As[k4 + 3][row] = f3;
  }
  for (int i = tid; i < 128 * 16; i += 256) {
    int c4 = (i & 15) << 2;
    int k = i >> 4;
    float4 v = *reinterpret_cast<const float4*>(W + (size_t)k * 64 + c4);
    *reinterpret_cast<float4*>(&Ws[k][c4]) = v;
  }
  __syncthreads();

  float acc[4][4] = {};
  #pragma unroll 8
  for (int k = 0; k < 128; ++k) {
    float4 a = *reinterpret_cast<const float4*>(&As[k][ty << 2]);
    float4 b = *reinterpret_cast<const float4*>(&Ws[k][tx << 2]);
    acc[0][0] += a.x * b.x; acc[0][1] += a.x * b.y; acc[0][2] += a.x * b.z; acc[0][3] += a.x * b.w;
    acc[1][0] += a.y * b.x; acc[1][1] += a.y * b.y; acc[1][2] += a.y * b.z; acc[1][3] += a.y * b.w;
    acc[2][0] += a.z * b.x; acc[2][1] += a.z * b.y; acc[2][2] += a.z * b.z; acc[2][3] += a.z * b.w;
    acc[3][0] += a.w * b.x; acc[3][1] += a.w * b.y; acc[3][2] += a.w * b.z; acc[3][3] += a.w * b.w;
  }
  #pragma unroll
  for (int r = 0; r < 4; ++r) {
    int gr = rowbase + (ty << 2) + r;
    if (gr < M) {
      uint2 p;
      p.x = pack2bf(acc[r][0], acc[r][1]);
      p.y = pack2bf(acc[r][2], acc[r][3]);
      *reinterpret_cast<uint2*>(C + (size_t)gr * 64 + (tx << 2)) = p;
    }
  }
}

// ---- agg layer 1: bf16 gather (256B rows), 4-way unrolled, bf16 out ----
__global__ __launch_bounds__(256) void agg128_relu_kernel(
    const u32* __restrict__ H, const int* __restrict__ rowstart,
    const int2* __restrict__ erec, const float* __restrict__ dinv,
    const float* __restrict__ bias, u32* __restrict__ out, int n) {
  int wid = (blockIdx.x * 256 + threadIdx.x) >> 6;
  int lane = threadIdx.x & 63;
  if (wid >= n) return;
  float dv = dinv[wid];
  float ns = dv * dv;
  u32 hv = H[(size_t)wid * 64 + lane];
  float a0 = ns * bflo(hv), a1 = ns * bfhi(hv);
  int e0 = rowstart[wid], e1 = rowstart[wid + 1];
  int e = e0;
  for (; e + 3 < e1; e += 4) {
    int2 r0 = erec[e], r1 = erec[e + 1], r2 = erec[e + 2], r3 = erec[e + 3];
    u32 v0 = H[(size_t)r0.x * 64 + lane];
    u32 v1 = H[(size_t)r1.x * 64 + lane];
    u32 v2 = H[(size_t)r2.x * 64 + lane];
    u32 v3 = H[(size_t)r3.x * 64 + lane];
    float w0 = __int_as_float(r0.y), w1 = __int_as_float(r1.y);
    float w2 = __int_as_float(r2.y), w3 = __int_as_float(r3.y);
    a0 += w0 * bflo(v0) + w1 * bflo(v1) + w2 * bflo(v2) + w3 * bflo(v3);
    a1 += w0 * bfhi(v0) + w1 * bfhi(v1) + w2 * bfhi(v2) + w3 * bfhi(v3);
  }
  for (; e < e1; ++e) {
    int2 r = erec[e];
    u32 v = H[(size_t)r.x * 64 + lane];
    float w = __int_as_float(r.y);
    a0 += w * bflo(v);
    a1 += w * bfhi(v);
  }
  float2 bb = reinterpret_cast<const float2*>(bias)[lane];
  a0 = fmaxf(a0 + bb.x, 0.f);
  a1 = fmaxf(a1 + bb.y, 0.f);
  out[(size_t)wid * 64 + lane] = pack2bf(a0, a1);
}

// ---- agg layer 2: bf16 gather (128B rows), 4-way unrolled, fp32 out ----
__global__ __launch_bounds__(256) void agg64_kernel(
    const u16* __restrict__ H, const int* __restrict__ rowstart,
    const int2* __restrict__ erec, const float* __restrict__ dinv,
    const float* __restrict__ bias, float* __restrict__ out, int n) {
  int wid = (blockIdx.x * 256 + threadIdx.x) >> 6;
  int lane = threadIdx.x & 63;
  if (wid >= n) return;
  float dv = dinv[wid];
  float ns = dv * dv;
  float a0 = ns * bflo((u32)H[(size_t)wid * 64 + lane]);
  int e0 = rowstart[wid], e1 = rowstart[wid + 1];
  int e = e0;
  for (; e + 3 < e1; e += 4) {
    int2 r0 = erec[e], r1 = erec[e + 1], r2 = erec[e + 2], r3 = erec[e + 3];
    float v0 = bflo((u32)H[(size_t)r0.x * 64 + lane]);
    float v1 = bflo((u32)H[(size_t)r1.x * 64 + lane]);
    float v2 = bflo((u32)H[(size_t)r2.x * 64 + lane]);
    float v3 = bflo((u32)H[(size_t)r3.x * 64 + lane]);
    a0 += __int_as_float(r0.y) * v0 + __int_as_float(r1.y) * v1 +
          __int_as_float(r2.y) * v2 + __int_as_float(r3.y) * v3;
  }
  for (; e < e1; ++e) {
    int2 r = erec[e];
    a0 += __int_as_float(r.y) * bflo((u32)H[(size_t)r.x * 64 + lane]);
  }
  out[(size_t)wid * 64 + lane] = a0 + bias[lane];
}

extern "C" void kernel_launch(void* const* d_in, const int* in_sizes, int n_in,
                              void* d_out, int out_size, void* d_ws, size_t ws_size,
                              hipStream_t stream) {
  const float* x  = (const float*)d_in[0];
  const int*   ei = (const int*)d_in[1];
  const float* ew = (const float*)d_in[2];
  const float* W1 = (const float*)d_in[3];
  const float* b1 = (const float*)d_in[4];
  const float* W2 = (const float*)d_in[5];
  const float* b2 = (const float*)d_in[6];
  float* out = (float*)d_out;
  const int N = in_sizes[0] / 128;
  const int E = in_sizes[2];
  const int* src = ei;
  const int* dst = ei + E;

  char* wsB = (char*)d_ws;
  size_t off = 0;
  auto alloc = [&](size_t bytes) {
    void* p = wsB + off;
    off += ((bytes + 255) / 256) * 256;
    return p;
  };
  u64*   packed = (u64*)alloc((size_t)N * 8);
  float* dinv   = (float*)alloc((size_t)N * 4);
  u16*   rank   = (u16*)alloc((size_t)E * 2);
  int*   rowst  = (int*)alloc((size_t)(N + 1) * 4);
  int*   bsum   = (int*)alloc(256 * 4);
  int*   boff   = (int*)alloc(256 * 4);
  int2*  erec   = (int2*)alloc((size_t)E * 8);
  u16*   h1     = (u16*)alloc((size_t)N * 128 * 2);  // bf16
  u16*   a1     = (u16*)alloc((size_t)N * 128 * 2);  // bf16
  u16*   h2     = h1;  // h1 dead after agg1; reuse

  const int nb = (N + 255) / 256;
  const int eb = (E + 255) / 256;          // degrank blocks
  const int nbx = (N + 63) / 64;
  const int gemm1Blocks = nbx * 2;
  const int nblk = (N + 1023) / 1024;      // 98 <= 256

  init_kernel<<<nb, 256, 0, stream>>>(packed, N);
  fused_dg_kernel<<<eb + gemm1Blocks, 256, 0, stream>>>(
      dst, ew, packed, rank, E, eb, x, W1, h1, N);
  scan1_kernel<<<nblk, 256, 0, stream>>>(packed, rowst, bsum, dinv, N);
  scan2_kernel<<<1, 256, 0, stream>>>(bsum, boff, nblk);
  scan3_kernel<<<nblk, 256, 0, stream>>>(rowst, boff, N, E);
  fill_kernel<<<eb, 256, 0, stream>>>(src, dst, ew, rank, dinv, rowst, erec, E);

  const int ab = (N + 3) / 4;
  agg128_relu_kernel<<<ab, 256, 0, stream>>>((const u32*)h1, rowst, erec, dinv, b1,
                                             (u32*)a1, N);
  gemm2_kernel<<<nbx, 256, 0, stream>>>(a1, W2, h2, N);
  agg64_kernel<<<ab, 256, 0, stream>>>(h2, rowst, erec, dinv, b2, out, N);
}